// Round 7
// baseline (111.457 us; speedup 1.0000x reference)
//
#include <hip/hip_runtime.h>
#include <stdint.h>

// ContrastiveLoss (SimCLR NT-Xent), B=4096, D=128, T=0.5
// loss = (1/2B) * sum_k log(denom_k)  -  (1/(B*T)) * sum_i dot(z_i, z_j_i)
//
// Round 8: revert persistence (R6: 2 blocks/CU pipelined LOST 7us to R5's 4
// blocks/CU simple -> kernel is TLP-bound). Keep R5's verified structure,
// squeeze occupancy: LDS = exactly 32 KB (bbuf only) -> 5 blocks/CU, 20
// waves (was 4/16). The 2.5 KB lds_cs/lds_row + the second barrier they
// required are gone: each wave exports its own quad-reduced column partial
// straight to partW[nt][4][N2] (plain stores, unique writer per entry,
// poison-safe); finalize folds the 4-way sum. One barrier per block total.
// Bijective XCD swizzle on the 2080-tile triangle (2080%8==0) groups
// same-A-band tiles per XCD L2.

#define TEMP 0.5f
// exp(x/T) = exp2(x * log2(e)/T); T=0.5 -> scale = 2*log2(e)
#define EXP2_SCALE 2.885390081777927f

typedef __bf16 bf16_t;
typedef bf16_t bf16x8 __attribute__((ext_vector_type(8)));
typedef float floatx4 __attribute__((ext_vector_type(4)));

typedef __attribute__((address_space(3))) uint32_t lds_u32;
typedef const __attribute__((address_space(1))) uint32_t glb_u32;

__device__ __forceinline__ unsigned short f32_to_bf16(float f) {
    union { float f; uint32_t u; } v; v.f = f;
    uint32_t u = v.u;
    uint32_t r = (u + 0x7FFFu + ((u >> 16) & 1u)) >> 16;  // RNE
    return (unsigned short)r;
}

__device__ __forceinline__ bf16x8 as_bf16x8(uint4 v) {
    union { uint4 u; bf16x8 b; } c; c.u = v; return c.b;
}

// Raw hardware exp2/log2; args bounded away from denormal/overflow range.
__device__ __forceinline__ float exp2_raw(float x) {
#if __has_builtin(__builtin_amdgcn_exp2f)
    return __builtin_amdgcn_exp2f(x);
#else
    float r; asm("v_exp_f32 %0, %1" : "=v"(r) : "v"(x)); return r;
#endif
}
__device__ __forceinline__ float log2_raw(float x) {
#if __has_builtin(__builtin_amdgcn_logf)
    return __builtin_amdgcn_logf(x);
#else
    float r; asm("v_log_f32 %0, %1" : "=v"(r) : "v"(x)); return r;
#endif
}

// ---------------------------------------------------------------------------
// Kernel 1: per-row L2 normalize, bf16 reps[2B][128]; pos[i] = dot(z_i,z_j).
// Zeroes out[0]. part buffers need no zeroing (single-writer scheme).
// ---------------------------------------------------------------------------
__global__ __launch_bounds__(256) void norm_pos_kernel(
        const float* __restrict__ p1, const float* __restrict__ p2,
        unsigned short* __restrict__ reps, float* __restrict__ pos,
        float* __restrict__ out, int B) {
    if (blockIdx.x == 0 && threadIdx.x == 0) out[0] = 0.f;

    const int slot = threadIdx.x >> 5;  // 8 row-slots per block
    const int h    = threadIdx.x & 31;  // 32 lanes x float4 = one 128-f row
    const int i = blockIdx.x * 8 + slot;
    if (i >= B) return;

    float4 a = ((const float4*)(p1 + (size_t)i * 128))[h];
    float4 b = ((const float4*)(p2 + (size_t)i * 128))[h];
    float ss1 = a.x*a.x + a.y*a.y + a.z*a.z + a.w*a.w;
    float ss2 = b.x*b.x + b.y*b.y + b.z*b.z + b.w*b.w;
    float d   = a.x*b.x + a.y*b.y + a.z*b.z + a.w*b.w;
    #pragma unroll
    for (int off = 16; off > 0; off >>= 1) {   // stays within each 32-half
        ss1 += __shfl_xor(ss1, off);
        ss2 += __shfl_xor(ss2, off);
        d   += __shfl_xor(d,   off);
    }
    float rn1 = rsqrtf(fmaxf(ss1, 1e-24f));
    float rn2 = rsqrtf(fmaxf(ss2, 1e-24f));

    ((ushort4*)reps)[(size_t)i * 32 + h] = make_ushort4(
        f32_to_bf16(a.x*rn1), f32_to_bf16(a.y*rn1),
        f32_to_bf16(a.z*rn1), f32_to_bf16(a.w*rn1));
    ((ushort4*)reps)[(size_t)(B + i) * 32 + h] = make_ushort4(
        f32_to_bf16(b.x*rn2), f32_to_bf16(b.y*rn2),
        f32_to_bf16(b.z*rn2), f32_to_bf16(b.w*rn2));

    if (h == 0) pos[i] = d * rn1 * rn2;
}

// ---------------------------------------------------------------------------
// Kernel 2: symmetric sim+exp; ONE barrier; LDS exactly 32 KB (5 blocks/CU).
// Block = 4 waves = 128x128 tile at triangle coords (by, bx), bx >= by.
// Wave w owns rows by*128 + w*32 as 2 A-tiles in registers. Whole 32 KB
// 128-col B strip staged once via global_load_lds in per-lane fragment order
// (ds_read_b128 conflict-free); A-frag global loads fly with the staging;
// one __syncthreads (implicit vmcnt(0)); 8 col-tiles back-to-back.
// Exports (all plain stores, unique writer, poison-safe):
//   rows: partR[bx][by*128 + row]  (float4 per quad, l16==0 lanes)
//   cols (off-diag): per-wave quad-reduced partials to
//         partW[(by*4 + wave)][bx*128 + col]  -- no cross-wave reduction,
//         no lds_cs, no second barrier.
// ---------------------------------------------------------------------------
__global__ __launch_bounds__(256, 5) void simexp_kernel(
        const unsigned short* __restrict__ reps,
        float* __restrict__ partR, float* __restrict__ partW,
        int nt, int N2, int nb) {
    const int tid  = threadIdx.x;
    const int wave = tid >> 6;
    const int lane = tid & 63;
    const int quad = lane >> 4;
    const int l16  = lane & 15;

    // bijective XCD swizzle (nb % 8 may be != 0 in general; m204 form)
    {
    }
    const int q8 = nb >> 3, r8 = nb & 7;
    const int xcd = (int)blockIdx.x & 7, idx = (int)blockIdx.x >> 3;
    int t = (xcd < r8 ? xcd * (q8 + 1) : r8 * (q8 + 1) + (xcd - r8) * q8) + idx;

    // linear tile id -> upper-triangle (by, bx); row 'by' has nt-by tiles
    int rem = t, by = 0;
    while (rem >= nt - by) { rem -= nt - by; ++by; }
    const int bx = by + rem;
    const bool diag = (bx == by);

    const int rowWave = by * 128 + wave * 32;  // this wave's 32 rows
    const int colBase = bx * 128;              // this block's 128 cols

    const uint4* g4 = (const uint4*)reps;  // 16 uint4 per 256-B row

    __shared__ __align__(16) unsigned short bbuf[8][2048];  // exactly 32 KB

    // stage whole B strip, per-lane fragment order:
    // panel ct at ct*4096 + tid*16 bytes (wave-uniform base + lane*16 = legal
    // global_load_lds dest); per-lane global src supplies fragment order.
    #pragma unroll
    for (int ct = 0; ct < 8; ++ct) {
        const unsigned short* src = reps
            + (size_t)(colBase + ct * 16 + l16) * 128 + wave * 32 + quad * 8;
        __builtin_amdgcn_global_load_lds(
            (glb_u32*)src, (lds_u32*)&bbuf[ct][tid * 8], 16, 0, 0);
    }

    // A-fragments: 2 row-tiles x 4 k-steps; global loads overlap staging
    bf16x8 a[2][4];
    #pragma unroll
    for (int tt = 0; tt < 2; ++tt)
        #pragma unroll
        for (int ks = 0; ks < 4; ++ks)
            a[tt][ks] = as_bf16x8(
                g4[(size_t)(rowWave + tt * 16 + l16) * 16 + ks * 4 + quad]);

    float rs[2][4];
    #pragma unroll
    for (int tt = 0; tt < 2; ++tt)
        #pragma unroll
        for (int r = 0; r < 4; ++r) rs[tt][r] = 0.f;
    float csa[8];
    #pragma unroll
    for (int ct = 0; ct < 8; ++ct) csa[ct] = 0.f;

    __syncthreads();  // the ONLY barrier: implicit vmcnt(0) -> B + A resident

    #pragma unroll
    for (int ct = 0; ct < 8; ++ct) {
        bf16x8 b[4];
        #pragma unroll
        for (int ks = 0; ks < 4; ++ks)
            b[ks] = *(const bf16x8*)&bbuf[ct][ks * 512 + lane * 8];

        floatx4 acc[2];
        acc[0] = (floatx4){0.f, 0.f, 0.f, 0.f};
        acc[1] = (floatx4){0.f, 0.f, 0.f, 0.f};
        #pragma unroll
        for (int ks = 0; ks < 4; ++ks) {
            acc[0] = __builtin_amdgcn_mfma_f32_16x16x32_bf16(a[0][ks], b[ks], acc[0], 0, 0, 0);
            acc[1] = __builtin_amdgcn_mfma_f32_16x16x32_bf16(a[1][ks], b[ks], acc[1], 0, 0, 0);
        }

        if (!diag) {
            float cs = 0.f;
            #pragma unroll
            for (int tt = 0; tt < 2; ++tt)
                #pragma unroll
                for (int r = 0; r < 4; ++r) {
                    float e = exp2_raw(acc[tt][r] * EXP2_SCALE);
                    rs[tt][r] += e;
                    cs += e;
                }
            // reduce across the 4 quads (same l16): lanes<16 hold the
            // per-WAVE column partial -- exported directly, no cross-wave
            cs += __shfl_xor(cs, 16);
            cs += __shfl_xor(cs, 32);
            csa[ct] = cs;
        } else {
            const int c = colBase + ct * 16 + l16;
            #pragma unroll
            for (int tt = 0; tt < 2; ++tt) {
                const int rb = rowWave + tt * 16 + quad * 4;
                #pragma unroll
                for (int r = 0; r < 4; ++r) {
                    float e = (rb + r == c) ? 0.f
                             : exp2_raw(acc[tt][r] * EXP2_SCALE);
                    rs[tt][r] += e;
                }
            }
        }
    }

    // row-side: reduce across the 16 columns of each quad, then direct
    // float4 stores (unique writer per partR entry)
    #pragma unroll
    for (int off = 1; off < 16; off <<= 1)
        #pragma unroll
        for (int tt = 0; tt < 2; ++tt)
            #pragma unroll
            for (int r = 0; r < 4; ++r)
                rs[tt][r] += __shfl_xor(rs[tt][r], off);

    if (l16 == 0) {
        #pragma unroll
        for (int tt = 0; tt < 2; ++tt) {
            float4 v = make_float4(rs[tt][0], rs[tt][1], rs[tt][2], rs[tt][3]);
            *(float4*)&partR[(size_t)bx * N2 + by * 128
                             + wave * 32 + tt * 16 + quad * 4] = v;
        }
    }

    // col-side (transposed half): per-wave partials, lanes<16, plain stores
    if (!diag && lane < 16) {
        float* pw = partW + (size_t)(by * 4 + wave) * N2 + colBase;
        #pragma unroll
        for (int ct = 0; ct < 8; ++ct)
            pw[ct * 16 + l16] = csa[ct];
    }
}

// ---------------------------------------------------------------------------
// Kernel 3: rowsum[r] = sum_{k>=by} partR[k][r] + sum_{k<by} sum_w
// partW[k*4+w][r]  (by = r/128; all reads coalesced, L2-resident), then
// out += mean(log(rowsum)) - sum(pos)/(B*T).
// ---------------------------------------------------------------------------
__global__ __launch_bounds__(256) void finalize_kernel(
        const float* __restrict__ partR, const float* __restrict__ partW,
        const float* __restrict__ pos, float* __restrict__ out,
        int N2, int B, int nt) {
    const int r  = blockIdx.x * 256 + threadIdx.x;  // grid covers N2 exactly
    const int by = r >> 7;

    float s = 0.f;
    for (int k = by; k < nt; ++k) s += partR[(size_t)k * N2 + r];
    for (int k = 0; k < by; ++k) {
        const float* pw = partW + (size_t)(k * 4) * N2 + r;
        s += (pw[0] + pw[(size_t)N2])
           + (pw[2 * (size_t)N2] + pw[3 * (size_t)N2]);
    }

    // log(x) = log2(x) * ln2
    float local = log2_raw(s) * (0.6931471805599453f / (float)N2);
    if (r < B) local -= pos[r] * (1.0f / ((float)B * TEMP));

    #pragma unroll
    for (int off = 32; off > 0; off >>= 1) local += __shfl_xor(local, off);

    __shared__ float wsum[4];
    const int wave = threadIdx.x >> 6, lane = threadIdx.x & 63;
    if (lane == 0) wsum[wave] = local;
    __syncthreads();
    if (threadIdx.x == 0)
        atomicAdd(out, wsum[0] + wsum[1] + wsum[2] + wsum[3]);
}

extern "C" void kernel_launch(void* const* d_in, const int* in_sizes, int n_in,
                              void* d_out, int out_size, void* d_ws, size_t ws_size,
                              hipStream_t stream) {
    const float* p1 = (const float*)d_in[0];
    const float* p2 = (const float*)d_in[1];
    float* out = (float*)d_out;

    const int B  = in_sizes[0] / 128;   // 4096
    const int N2 = 2 * B;               // 8192
    const int nt = N2 / 128;            // 64 row/col tiles
    const int nb = nt * (nt + 1) / 2;   // 2080 upper-triangle tiles

    // ws layout: [reps bf16: N2*256 B][partR: nt*N2*4 B][partW: nt*4*N2*4 B]
    //            [pos: B*4 B]
    unsigned short* reps = (unsigned short*)d_ws;
    float* partR = (float*)((char*)d_ws + (size_t)N2 * 256);
    float* partW = partR + (size_t)nt * N2;
    float* pos   = partW + (size_t)nt * 4 * N2;

    norm_pos_kernel<<<dim3((B + 7) / 8), dim3(256), 0, stream>>>(
        p1, p2, reps, pos, out, B);

    simexp_kernel<<<dim3(nb), dim3(256), 0, stream>>>(
        reps, partR, partW, nt, N2, nb);

    finalize_kernel<<<dim3(N2 / 256), dim3(256), 0, stream>>>(
        partR, partW, pos, out, N2, B, nt);
}

// Round 8
// 103.434 us; speedup vs baseline: 1.0776x; 1.0776x over previous
//
#include <hip/hip_runtime.h>
#include <stdint.h>

// ContrastiveLoss (SimCLR NT-Xent), B=4096, D=128, T=0.5
// loss = (1/2B) * sum_k log(denom_k)  -  (1/(B*T)) * sum_i dot(z_i, z_j_i)
//
// Round 9: R7 regressed 2x (111us): prime suspect = __launch_bounds__(256,5)
// forcing VGPR<=102 -> scratch spill in the fully-unrolled ct loop holding
// csa[8]; secondary = XCD swizzle scattering dispatch order. This round
// keeps R7's two sound ideas (ONE barrier per block; per-wave col export to
// partW so LDS = exactly 32 KB -> 5 blocks/CU) and removes both suspects:
// no launch-bounds minimum, no swizzle, and csa[] eliminated entirely (col
// partial cs stored to partW inside the ct loop, lanes<16, fire-and-forget)
// to cut register pressure below the 5-waves/SIMD threshold naturally.
// Tile math / fragment layout / export mapping identical to verified R5.

#define TEMP 0.5f
// exp(x/T) = exp2(x * log2(e)/T); T=0.5 -> scale = 2*log2(e)
#define EXP2_SCALE 2.885390081777927f

typedef __bf16 bf16_t;
typedef bf16_t bf16x8 __attribute__((ext_vector_type(8)));
typedef float floatx4 __attribute__((ext_vector_type(4)));

typedef __attribute__((address_space(3))) uint32_t lds_u32;
typedef const __attribute__((address_space(1))) uint32_t glb_u32;

__device__ __forceinline__ unsigned short f32_to_bf16(float f) {
    union { float f; uint32_t u; } v; v.f = f;
    uint32_t u = v.u;
    uint32_t r = (u + 0x7FFFu + ((u >> 16) & 1u)) >> 16;  // RNE
    return (unsigned short)r;
}

__device__ __forceinline__ bf16x8 as_bf16x8(uint4 v) {
    union { uint4 u; bf16x8 b; } c; c.u = v; return c.b;
}

// Raw hardware exp2/log2; args bounded away from denormal/overflow range.
__device__ __forceinline__ float exp2_raw(float x) {
#if __has_builtin(__builtin_amdgcn_exp2f)
    return __builtin_amdgcn_exp2f(x);
#else
    float r; asm("v_exp_f32 %0, %1" : "=v"(r) : "v"(x)); return r;
#endif
}
__device__ __forceinline__ float log2_raw(float x) {
#if __has_builtin(__builtin_amdgcn_logf)
    return __builtin_amdgcn_logf(x);
#else
    float r; asm("v_log_f32 %0, %1" : "=v"(r) : "v"(x)); return r;
#endif
}

// ---------------------------------------------------------------------------
// Kernel 1: per-row L2 normalize, bf16 reps[2B][128]; pos[i] = dot(z_i,z_j).
// Zeroes out[0]. part buffers need no zeroing (single-writer scheme).
// ---------------------------------------------------------------------------
__global__ __launch_bounds__(256) void norm_pos_kernel(
        const float* __restrict__ p1, const float* __restrict__ p2,
        unsigned short* __restrict__ reps, float* __restrict__ pos,
        float* __restrict__ out, int B) {
    if (blockIdx.x == 0 && threadIdx.x == 0) out[0] = 0.f;

    const int slot = threadIdx.x >> 5;  // 8 row-slots per block
    const int h    = threadIdx.x & 31;  // 32 lanes x float4 = one 128-f row
    const int i = blockIdx.x * 8 + slot;
    if (i >= B) return;

    float4 a = ((const float4*)(p1 + (size_t)i * 128))[h];
    float4 b = ((const float4*)(p2 + (size_t)i * 128))[h];
    float ss1 = a.x*a.x + a.y*a.y + a.z*a.z + a.w*a.w;
    float ss2 = b.x*b.x + b.y*b.y + b.z*b.z + b.w*b.w;
    float d   = a.x*b.x + a.y*b.y + a.z*b.z + a.w*b.w;
    #pragma unroll
    for (int off = 16; off > 0; off >>= 1) {   // stays within each 32-half
        ss1 += __shfl_xor(ss1, off);
        ss2 += __shfl_xor(ss2, off);
        d   += __shfl_xor(d,   off);
    }
    float rn1 = rsqrtf(fmaxf(ss1, 1e-24f));
    float rn2 = rsqrtf(fmaxf(ss2, 1e-24f));

    ((ushort4*)reps)[(size_t)i * 32 + h] = make_ushort4(
        f32_to_bf16(a.x*rn1), f32_to_bf16(a.y*rn1),
        f32_to_bf16(a.z*rn1), f32_to_bf16(a.w*rn1));
    ((ushort4*)reps)[(size_t)(B + i) * 32 + h] = make_ushort4(
        f32_to_bf16(b.x*rn2), f32_to_bf16(b.y*rn2),
        f32_to_bf16(b.z*rn2), f32_to_bf16(b.w*rn2));

    if (h == 0) pos[i] = d * rn1 * rn2;
}

// ---------------------------------------------------------------------------
// Kernel 2: symmetric sim+exp; ONE barrier; LDS exactly 32 KB.
// Block = 4 waves = 128x128 tile at triangle coords (by, bx), bx >= by.
// Wave w owns rows by*128 + w*32 as 2 A-tiles in registers. Whole 32 KB
// 128-col B strip staged once via global_load_lds in per-lane fragment order
// (ds_read_b128 conflict-free); A-frag global loads fly with the staging;
// one __syncthreads (implicit vmcnt(0)); 8 col-tiles back-to-back.
// Exports (all plain stores, unique writer, poison-safe):
//   rows: partR[bx][by*128 + row]  (float4 per quad, l16==0 lanes)
//   cols (off-diag): per-wave quad-reduced partial stored per-ct inside the
//         loop to partW[(by*4 + wave)][bx*128 + col] -- no csa regs, no
//         lds_cs, no second barrier.
// ---------------------------------------------------------------------------
__global__ __launch_bounds__(256) void simexp_kernel(
        const unsigned short* __restrict__ reps,
        float* __restrict__ partR, float* __restrict__ partW,
        int nt, int N2) {
    const int tid  = threadIdx.x;
    const int wave = tid >> 6;
    const int lane = tid & 63;
    const int quad = lane >> 4;
    const int l16  = lane & 15;

    // linear tile id -> upper-triangle (by, bx); row 'by' has nt-by tiles
    int rem = (int)blockIdx.x, by = 0;
    while (rem >= nt - by) { rem -= nt - by; ++by; }
    const int bx = by + rem;
    const bool diag = (bx == by);

    const int rowWave = by * 128 + wave * 32;  // this wave's 32 rows
    const int colBase = bx * 128;              // this block's 128 cols

    const uint4* g4 = (const uint4*)reps;  // 16 uint4 per 256-B row

    __shared__ __align__(16) unsigned short bbuf[8][2048];  // exactly 32 KB

    // stage whole B strip, per-lane fragment order:
    // panel ct at ct*4096 + tid*16 bytes (wave-uniform base + lane*16 = legal
    // global_load_lds dest); per-lane global src supplies fragment order.
    #pragma unroll
    for (int ct = 0; ct < 8; ++ct) {
        const unsigned short* src = reps
            + (size_t)(colBase + ct * 16 + l16) * 128 + wave * 32 + quad * 8;
        __builtin_amdgcn_global_load_lds(
            (glb_u32*)src, (lds_u32*)&bbuf[ct][tid * 8], 16, 0, 0);
    }

    // A-fragments: 2 row-tiles x 4 k-steps; global loads overlap staging
    bf16x8 a[2][4];
    #pragma unroll
    for (int tt = 0; tt < 2; ++tt)
        #pragma unroll
        for (int ks = 0; ks < 4; ++ks)
            a[tt][ks] = as_bf16x8(
                g4[(size_t)(rowWave + tt * 16 + l16) * 16 + ks * 4 + quad]);

    float rs[2][4];
    #pragma unroll
    for (int tt = 0; tt < 2; ++tt)
        #pragma unroll
        for (int r = 0; r < 4; ++r) rs[tt][r] = 0.f;

    float* pw = partW + (size_t)(by * 4 + wave) * N2 + colBase;

    __syncthreads();  // the ONLY barrier: implicit vmcnt(0) -> B + A resident

    #pragma unroll
    for (int ct = 0; ct < 8; ++ct) {
        bf16x8 b[4];
        #pragma unroll
        for (int ks = 0; ks < 4; ++ks)
            b[ks] = *(const bf16x8*)&bbuf[ct][ks * 512 + lane * 8];

        floatx4 acc[2];
        acc[0] = (floatx4){0.f, 0.f, 0.f, 0.f};
        acc[1] = (floatx4){0.f, 0.f, 0.f, 0.f};
        #pragma unroll
        for (int ks = 0; ks < 4; ++ks) {
            acc[0] = __builtin_amdgcn_mfma_f32_16x16x32_bf16(a[0][ks], b[ks], acc[0], 0, 0, 0);
            acc[1] = __builtin_amdgcn_mfma_f32_16x16x32_bf16(a[1][ks], b[ks], acc[1], 0, 0, 0);
        }

        if (!diag) {
            float cs = 0.f;
            #pragma unroll
            for (int tt = 0; tt < 2; ++tt)
                #pragma unroll
                for (int r = 0; r < 4; ++r) {
                    float e = exp2_raw(acc[tt][r] * EXP2_SCALE);
                    rs[tt][r] += e;
                    cs += e;
                }
            // reduce across the 4 quads (same l16) -> per-wave col partial;
            // store immediately (fire-and-forget), no csa register array
            cs += __shfl_xor(cs, 16);
            cs += __shfl_xor(cs, 32);
            if (lane < 16) pw[ct * 16 + l16] = cs;
        } else {
            const int c = colBase + ct * 16 + l16;
            #pragma unroll
            for (int tt = 0; tt < 2; ++tt) {
                const int rb = rowWave + tt * 16 + quad * 4;
                #pragma unroll
                for (int r = 0; r < 4; ++r) {
                    float e = (rb + r == c) ? 0.f
                             : exp2_raw(acc[tt][r] * EXP2_SCALE);
                    rs[tt][r] += e;
                }
            }
        }
    }

    // row-side: reduce across the 16 columns of each quad, then direct
    // float4 stores (unique writer per partR entry)
    #pragma unroll
    for (int off = 1; off < 16; off <<= 1)
        #pragma unroll
        for (int tt = 0; tt < 2; ++tt)
            #pragma unroll
            for (int r = 0; r < 4; ++r)
                rs[tt][r] += __shfl_xor(rs[tt][r], off);

    if (l16 == 0) {
        #pragma unroll
        for (int tt = 0; tt < 2; ++tt) {
            float4 v = make_float4(rs[tt][0], rs[tt][1], rs[tt][2], rs[tt][3]);
            *(float4*)&partR[(size_t)bx * N2 + by * 128
                             + wave * 32 + tt * 16 + quad * 4] = v;
        }
    }
}

// ---------------------------------------------------------------------------
// Kernel 3: rowsum[r] = sum_{k>=by} partR[k][r] + sum_{k<by} sum_w
// partW[k*4+w][r]  (by = r/128; all reads coalesced, L2-resident), then
// out += mean(log(rowsum)) - sum(pos)/(B*T).
// ---------------------------------------------------------------------------
__global__ __launch_bounds__(256) void finalize_kernel(
        const float* __restrict__ partR, const float* __restrict__ partW,
        const float* __restrict__ pos, float* __restrict__ out,
        int N2, int B, int nt) {
    const int r  = blockIdx.x * 256 + threadIdx.x;  // grid covers N2 exactly
    const int by = r >> 7;

    float s = 0.f;
    for (int k = by; k < nt; ++k) s += partR[(size_t)k * N2 + r];
    for (int k = 0; k < by; ++k) {
        const float* pw = partW + (size_t)(k * 4) * N2 + r;
        s += (pw[0] + pw[(size_t)N2])
           + (pw[2 * (size_t)N2] + pw[3 * (size_t)N2]);
    }

    // log(x) = log2(x) * ln2
    float local = log2_raw(s) * (0.6931471805599453f / (float)N2);
    if (r < B) local -= pos[r] * (1.0f / ((float)B * TEMP));

    #pragma unroll
    for (int off = 32; off > 0; off >>= 1) local += __shfl_xor(local, off);

    __shared__ float wsum[4];
    const int wave = threadIdx.x >> 6, lane = threadIdx.x & 63;
    if (lane == 0) wsum[wave] = local;
    __syncthreads();
    if (threadIdx.x == 0)
        atomicAdd(out, wsum[0] + wsum[1] + wsum[2] + wsum[3]);
}

extern "C" void kernel_launch(void* const* d_in, const int* in_sizes, int n_in,
                              void* d_out, int out_size, void* d_ws, size_t ws_size,
                              hipStream_t stream) {
    const float* p1 = (const float*)d_in[0];
    const float* p2 = (const float*)d_in[1];
    float* out = (float*)d_out;

    const int B  = in_sizes[0] / 128;   // 4096
    const int N2 = 2 * B;               // 8192
    const int nt = N2 / 128;            // 64 row/col tiles
    const int nb = nt * (nt + 1) / 2;   // 2080 upper-triangle tiles

    // ws layout: [reps bf16: N2*256 B][partR: nt*N2*4 B][partW: nt*4*N2*4 B]
    //            [pos: B*4 B]
    unsigned short* reps = (unsigned short*)d_ws;
    float* partR = (float*)((char*)d_ws + (size_t)N2 * 256);
    float* partW = partR + (size_t)nt * N2;
    float* pos   = partW + (size_t)nt * 4 * N2;

    norm_pos_kernel<<<dim3((B + 7) / 8), dim3(256), 0, stream>>>(
        p1, p2, reps, pos, out, B);

    simexp_kernel<<<dim3(nb), dim3(256), 0, stream>>>(
        reps, partR, partW, nt, N2);

    finalize_kernel<<<dim3(N2 / 256), dim3(256), 0, stream>>>(
        partR, partW, pos, out, N2, B, nt);
}

// Round 9
// 85.778 us; speedup vs baseline: 1.2994x; 1.2058x over previous
//
#include <hip/hip_runtime.h>
#include <stdint.h>

// ContrastiveLoss (SimCLR NT-Xent), B=4096, D=128, T=0.5
// loss = (1/2B) * sum_k log(denom_k)  -  (1/(B*T)) * sum_i dot(z_i, z_j_i)
//
// FINAL (round-5 configuration, measured 85.9 us — session best).
// Structure: 3 plain dispatches.
//  - norm_pos: float4-vectorized L2 normalize -> bf16 reps; pos[i]=dot(zi,zj).
//  - simexp: symmetric upper-triangle 128x128 tiles (2080 blocks, 0.52x
//    work); whole 32 KB B strip staged once per block via global_load_lds
//    in per-lane fragment order (ds_read_b128 conflict-free); ONE stage
//    barrier; 8 col-tiles back-to-back; raw v_exp_f32 (args bounded |x|<=2.9
//    -> libm fixup unnecessary; ~4x VALU cut vs exp2f); exports via LDS +
//    plain coalesced stores into single-writer part[] (atomic-free: the
//    earlier rowsum atomicAdds serialized ~1040 same-line fp atomics).
//  - finalize: per-row sum of nt partials + log + pos term.
// Post-R5 experiments all regressed and are reverted: persistence (93.1),
// occupancy-push bundle (111.5), in-loop per-wave col export (103.4) --
// the kernel is TLP/barrier-structure-bound and this configuration won.

#define TEMP 0.5f
// exp(x/T) = exp2(x * log2(e)/T); T=0.5 -> scale = 2*log2(e)
#define EXP2_SCALE 2.885390081777927f

typedef __bf16 bf16_t;
typedef bf16_t bf16x8 __attribute__((ext_vector_type(8)));
typedef float floatx4 __attribute__((ext_vector_type(4)));

typedef __attribute__((address_space(3))) uint32_t lds_u32;
typedef const __attribute__((address_space(1))) uint32_t glb_u32;

__device__ __forceinline__ unsigned short f32_to_bf16(float f) {
    union { float f; uint32_t u; } v; v.f = f;
    uint32_t u = v.u;
    uint32_t r = (u + 0x7FFFu + ((u >> 16) & 1u)) >> 16;  // RNE
    return (unsigned short)r;
}

__device__ __forceinline__ bf16x8 as_bf16x8(uint4 v) {
    union { uint4 u; bf16x8 b; } c; c.u = v; return c.b;
}

// Raw hardware exp2/log2; args bounded away from denormal/overflow range.
__device__ __forceinline__ float exp2_raw(float x) {
#if __has_builtin(__builtin_amdgcn_exp2f)
    return __builtin_amdgcn_exp2f(x);
#else
    float r; asm("v_exp_f32 %0, %1" : "=v"(r) : "v"(x)); return r;
#endif
}
__device__ __forceinline__ float log2_raw(float x) {
#if __has_builtin(__builtin_amdgcn_logf)
    return __builtin_amdgcn_logf(x);
#else
    float r; asm("v_log_f32 %0, %1" : "=v"(r) : "v"(x)); return r;
#endif
}

// ---------------------------------------------------------------------------
// Kernel 1: per-row L2 normalize, bf16 reps[2B][128]; pos[i] = dot(z_i,z_j).
// Zeroes out[0] (no memset dispatch; part[] needs no zeroing at all).
// ---------------------------------------------------------------------------
__global__ __launch_bounds__(256) void norm_pos_kernel(
        const float* __restrict__ p1, const float* __restrict__ p2,
        unsigned short* __restrict__ reps, float* __restrict__ pos,
        float* __restrict__ out, int B) {
    if (blockIdx.x == 0 && threadIdx.x == 0) out[0] = 0.f;

    const int slot = threadIdx.x >> 5;  // 8 row-slots per block
    const int h    = threadIdx.x & 31;  // 32 lanes x float4 = one 128-f row
    const int i = blockIdx.x * 8 + slot;
    if (i >= B) return;

    float4 a = ((const float4*)(p1 + (size_t)i * 128))[h];
    float4 b = ((const float4*)(p2 + (size_t)i * 128))[h];
    float ss1 = a.x*a.x + a.y*a.y + a.z*a.z + a.w*a.w;
    float ss2 = b.x*b.x + b.y*b.y + b.z*b.z + b.w*b.w;
    float d   = a.x*b.x + a.y*b.y + a.z*b.z + a.w*b.w;
    #pragma unroll
    for (int off = 16; off > 0; off >>= 1) {   // stays within each 32-half
        ss1 += __shfl_xor(ss1, off);
        ss2 += __shfl_xor(ss2, off);
        d   += __shfl_xor(d,   off);
    }
    float rn1 = rsqrtf(fmaxf(ss1, 1e-24f));
    float rn2 = rsqrtf(fmaxf(ss2, 1e-24f));

    ((ushort4*)reps)[(size_t)i * 32 + h] = make_ushort4(
        f32_to_bf16(a.x*rn1), f32_to_bf16(a.y*rn1),
        f32_to_bf16(a.z*rn1), f32_to_bf16(a.w*rn1));
    ((ushort4*)reps)[(size_t)(B + i) * 32 + h] = make_ushort4(
        f32_to_bf16(b.x*rn2), f32_to_bf16(b.y*rn2),
        f32_to_bf16(b.z*rn2), f32_to_bf16(b.w*rn2));

    if (h == 0) pos[i] = d * rn1 * rn2;
}

// ---------------------------------------------------------------------------
// Kernel 2: symmetric sim+exp, atomic-free export.
// Block = 4 waves = 128x128 tile at triangle coords (by, bx), bx >= by.
// Wave w owns rows by*128 + w*32 as 2 A-tiles in registers. Whole 32 KB
// 128-col B strip staged once via global_load_lds in per-lane fragment order
// (ds_read_b128 conflict-free); one barrier; 8 col-tiles back-to-back.
// Exports: row-sums -> lds_row -> part[bx][by*128 + tid] (one 512-B
// coalesced store); col-sums (transposed half, off-diag only) -> per-wave
// lds_cs slots -> part[by][bx*128 + tid]. Zero atomics.
// ---------------------------------------------------------------------------
__global__ __launch_bounds__(256) void simexp_kernel(
        const unsigned short* __restrict__ reps,
        float* __restrict__ part, int nt, int N2) {
    const int tid  = threadIdx.x;
    const int wave = tid >> 6;
    const int lane = tid & 63;
    const int quad = lane >> 4;
    const int l16  = lane & 15;

    // linear block id -> upper-triangle (by, bx); row 'by' has nt-by tiles
    int rem = (int)blockIdx.x;
    int by = 0;
    while (rem >= nt - by) { rem -= nt - by; ++by; }
    const int bx = by + rem;
    const bool diag = (bx == by);

    const int rowWave = by * 128 + wave * 32;  // this wave's 32 rows
    const int colBase = bx * 128;              // this block's 128 cols

    const uint4* g4 = (const uint4*)reps;  // 16 uint4 per 256-B row

    __shared__ __align__(16) unsigned short bbuf[8][2048];  // 32 KB B strip
    __shared__ float lds_row[128];                          // row-sum export
    __shared__ float lds_cs[4][128];                        // per-wave col sums

    // stage whole B strip, per-lane fragment order:
    // panel ct at ct*4096 + tid*16 bytes (wave-uniform base + lane*16: legal
    // global_load_lds dest); per-lane global src supplies fragment order.
    #pragma unroll
    for (int ct = 0; ct < 8; ++ct) {
        const unsigned short* src = reps
            + (size_t)(colBase + ct * 16 + l16) * 128 + wave * 32 + quad * 8;
        __builtin_amdgcn_global_load_lds(
            (glb_u32*)src, (lds_u32*)&bbuf[ct][tid * 8], 16, 0, 0);
    }

    // A-fragments: 2 row-tiles x 4 k-steps; global loads overlap staging
    bf16x8 a[2][4];
    #pragma unroll
    for (int tt = 0; tt < 2; ++tt)
        #pragma unroll
        for (int ks = 0; ks < 4; ++ks)
            a[tt][ks] = as_bf16x8(
                g4[(size_t)(rowWave + tt * 16 + l16) * 16 + ks * 4 + quad]);

    float rs[2][4];
    #pragma unroll
    for (int tt = 0; tt < 2; ++tt)
        #pragma unroll
        for (int r = 0; r < 4; ++r) rs[tt][r] = 0.f;

    __syncthreads();  // implicit vmcnt(0): B strip + A resident

    #pragma unroll
    for (int ct = 0; ct < 8; ++ct) {
        bf16x8 b[4];
        #pragma unroll
        for (int ks = 0; ks < 4; ++ks)
            b[ks] = *(const bf16x8*)&bbuf[ct][ks * 512 + lane * 8];

        floatx4 acc[2];
        acc[0] = (floatx4){0.f, 0.f, 0.f, 0.f};
        acc[1] = (floatx4){0.f, 0.f, 0.f, 0.f};
        #pragma unroll
        for (int ks = 0; ks < 4; ++ks) {
            acc[0] = __builtin_amdgcn_mfma_f32_16x16x32_bf16(a[0][ks], b[ks], acc[0], 0, 0, 0);
            acc[1] = __builtin_amdgcn_mfma_f32_16x16x32_bf16(a[1][ks], b[ks], acc[1], 0, 0, 0);
        }

        if (!diag) {
            float cs = 0.f;
            #pragma unroll
            for (int tt = 0; tt < 2; ++tt)
                #pragma unroll
                for (int r = 0; r < 4; ++r) {
                    float e = exp2_raw(acc[tt][r] * EXP2_SCALE);
                    rs[tt][r] += e;
                    cs += e;
                }
            cs += __shfl_xor(cs, 16);   // reduce across the 4 quads
            cs += __shfl_xor(cs, 32);
            if (lane < 16) lds_cs[wave][ct * 16 + lane] = cs;
        } else {
            const int c = colBase + ct * 16 + l16;
            #pragma unroll
            for (int tt = 0; tt < 2; ++tt) {
                const int rb = rowWave + tt * 16 + quad * 4;
                #pragma unroll
                for (int r = 0; r < 4; ++r) {
                    float e = (rb + r == c) ? 0.f
                             : exp2_raw(acc[tt][r] * EXP2_SCALE);
                    rs[tt][r] += e;
                }
            }
        }
    }

    // row-side: reduce rs across the 16 columns of each quad -> lds_row
    #pragma unroll
    for (int off = 1; off < 16; off <<= 1)
        #pragma unroll
        for (int tt = 0; tt < 2; ++tt)
            #pragma unroll
            for (int r = 0; r < 4; ++r)
                rs[tt][r] += __shfl_xor(rs[tt][r], off);

    if (l16 == 0) {
        #pragma unroll
        for (int tt = 0; tt < 2; ++tt)
            #pragma unroll
            for (int r = 0; r < 4; ++r)
                lds_row[wave * 32 + tt * 16 + quad * 4 + r] = rs[tt][r];
    }

    __syncthreads();

    // plain coalesced stores; each part[k][r] has exactly one writer:
    //   k >= band(r): tile (band(r), k) row-export
    //   k <  band(r): tile (k, band(r)) col-export
    if (tid < 128) {
        part[(size_t)bx * N2 + by * 128 + tid] = lds_row[tid];
        if (!diag)
            part[(size_t)by * N2 + colBase + tid] =
                lds_cs[0][tid] + lds_cs[1][tid] + lds_cs[2][tid] + lds_cs[3][tid];
    }
}

// ---------------------------------------------------------------------------
// Kernel 3: rowsum[r] = sum_k part[k][r] (coalesced, L2-resident), then
// out += mean(log(rowsum)) - sum(pos)/(B*T). One thread per row.
// ---------------------------------------------------------------------------
__global__ __launch_bounds__(256) void finalize_kernel(
        const float* __restrict__ part, const float* __restrict__ pos,
        float* __restrict__ out, int N2, int B, int nt) {
    const int r = blockIdx.x * 256 + threadIdx.x;   // grid covers N2 exactly
    float s = 0.f;
    #pragma unroll 8
    for (int k = 0; k < nt; ++k) s += part[(size_t)k * N2 + r];

    // log(x) = log2(x) * ln2
    float local = log2_raw(s) * (0.6931471805599453f / (float)N2);
    if (r < B) local -= pos[r] * (1.0f / ((float)B * TEMP));

    #pragma unroll
    for (int off = 32; off > 0; off >>= 1) local += __shfl_xor(local, off);

    __shared__ float wsum[4];
    const int wave = threadIdx.x >> 6, lane = threadIdx.x & 63;
    if (lane == 0) wsum[wave] = local;
    __syncthreads();
    if (threadIdx.x == 0)
        atomicAdd(out, wsum[0] + wsum[1] + wsum[2] + wsum[3]);
}

extern "C" void kernel_launch(void* const* d_in, const int* in_sizes, int n_in,
                              void* d_out, int out_size, void* d_ws, size_t ws_size,
                              hipStream_t stream) {
    const float* p1 = (const float*)d_in[0];
    const float* p2 = (const float*)d_in[1];
    float* out = (float*)d_out;

    const int B  = in_sizes[0] / 128;   // 4096
    const int N2 = 2 * B;               // 8192
    const int nt = N2 / 128;            // 64 row/col tiles
    const int nb = nt * (nt + 1) / 2;   // 2080 upper-triangle tiles

    // ws layout: [reps bf16: N2*256 B][part fp32: nt*N2*4 B][pos fp32: B*4 B]
    unsigned short* reps = (unsigned short*)d_ws;
    float* part = (float*)((char*)d_ws + (size_t)N2 * 256);
    float* pos  = part + (size_t)nt * N2;

    norm_pos_kernel<<<dim3((B + 7) / 8), dim3(256), 0, stream>>>(
        p1, p2, reps, pos, out, B);

    simexp_kernel<<<dim3(nb), dim3(256), 0, stream>>>(reps, part, nt, N2);

    finalize_kernel<<<dim3(N2 / 256), dim3(256), 0, stream>>>(
        part, pos, out, N2, B, nt);
}